// Round 1
// baseline (193.920 us; speedup 1.0000x reference)
//
#include <hip/hip_runtime.h>

typedef __attribute__((ext_vector_type(8))) short short8;
typedef __attribute__((ext_vector_type(4))) float f32x4;

#define LN1000_OVER_512 0.0134917095f

__device__ __forceinline__ short f2bf(float x) {
  unsigned u = __float_as_uint(x);
  unsigned r = (u + 0x7FFFu + ((u >> 16) & 1u)) >> 16;
  return (short)r;
}

// ws layout (f32 indices)
#define EPS_OFF   0        // [32][2048]
#define IMGX_OFF  65536    // [64][256]
#define IMGY_OFF  81920    // [48][256]
#define PARTV_OFF 94208    // [8][32][512]
#define VBF_OFF   225280   // bf16 [32][512] in 8192 f32 slots
#define BVEC_OFF  233472   // [(n*49+k)][256] f32
#define GX_OFF    634880   // [(n*49+k)][64] f32
#define GY_OFF    735232   // [(n*49+k)][48] f32
#define APPT_OFF  810496   // [4][3072][52] f32 (k padded 49->52)

__global__ __launch_bounds__(256) void k_pre(const float* __restrict__ rois,
                                             const float* __restrict__ W_im,
                                             float* __restrict__ ws) {
  __shared__ float el[512];
  int bid = blockIdx.x, tid = threadIdx.x;
  if (bid < 112) {
    bool isx = bid < 64;
    int pos = isx ? bid : bid - 64;
    float z = (float)pos;
    for (int e = tid; e < 512; e += 256) {
      float inv = (e < 256) ? __expf(-LN1000_OVER_512 * (float)(2*e+1))
                            : __expf(-LN1000_OVER_512 * (float)(2*(e-256)));
      el[e] = (e < 256) ? sinf(z * inv) : cosf(z * inv);
    }
    __syncthreads();
    const float* wrow = W_im + tid * 1024 + (isx ? 0 : 512);
    float acc = 0.f;
    #pragma unroll 4
    for (int d = 0; d < 512; d += 4) {
      float4 wv = *(const float4*)(wrow + d);
      acc += wv.x*el[d] + wv.y*el[d+1] + wv.z*el[d+2] + wv.w*el[d+3];
    }
    if (isx) ws[IMGX_OFF + pos*256 + tid] = acc;
    else     ws[IMGY_OFF + pos*256 + tid] = acc;
  } else {
    int id0 = (bid - 112) * 256 + tid;   // 8 blocks x 256 = 2048 threads
    for (int r = 0; r < 32; ++r) {
      int id = id0 + r * 2048;           // 65536 eps elements
      int n = id >> 11;
      int f = id & 2047;
      int c = f >> 9;
      int e = f & 511;
      float z = rois[n*5 + 1 + c];
      float inv = (e < 256) ? __expf(-LN1000_OVER_512 * (float)(2*e+1))
                            : __expf(-LN1000_OVER_512 * (float)(2*(e-256)));
      ws[EPS_OFF + id] = (e < 256) ? sinf(z*inv) : cosf(z*inv);
    }
  }
}

// v = eps(32x2048) . V_box(512x2048)^T   -- grid K-split x8 into PARTV
__global__ __launch_bounds__(256) void k_v(const float* __restrict__ V_box,
                                           float* __restrict__ ws) {
  __shared__ __align__(16) short Al[32*264];
  __shared__ __align__(16) short Bl[32*264];
  int tid = threadIdx.x;
  int ntb = blockIdx.x & 15;
  int ks  = blockIdx.x >> 4;
  int k0  = ks * 256;
  int d0  = ntb * 32;
  for (int j = 0; j < 32; ++j) {
    int id = tid + j*256;
    int n = id >> 8, kk = id & 255;
    Al[n*264 + kk] = f2bf(ws[EPS_OFF + n*2048 + k0 + kk]);
  }
  for (int j = 0; j < 32; ++j) {
    int id = tid + j*256;
    int dd = id >> 8, kk = id & 255;
    Bl[dd*264 + kk] = f2bf(V_box[(d0+dd)*2048 + k0 + kk]);
  }
  __syncthreads();
  int w = tid >> 6, lane = tid & 63;
  int q = lane >> 4, m = lane & 15;
  int m0 = (w & 1) * 16, n0 = (w >> 1) * 16;
  f32x4 acc = {0.f,0.f,0.f,0.f};
  const short* ap = Al + (m0 + m)*264 + q*8;
  const short* bp = Bl + (n0 + m)*264 + q*8;
  #pragma unroll
  for (int kk = 0; kk < 8; ++kk) {
    short8 a = *(const short8*)(ap + kk*32);
    short8 b = *(const short8*)(bp + kk*32);
    acc = __builtin_amdgcn_mfma_f32_16x16x32_bf16(a, b, acc, 0, 0, 0);
  }
  float* outp = ws + PARTV_OFF + ks*16384;
  #pragma unroll
  for (int r = 0; r < 4; ++r) {
    int row = m0 + q*4 + r;
    int col = d0 + n0 + m;
    outp[row*512 + col] = acc[r];
  }
}

__global__ __launch_bounds__(256) void k_vred(float* __restrict__ ws) {
  int i = blockIdx.x*256 + threadIdx.x;   // 64 blocks -> 16384
  float s = 0.f;
  #pragma unroll
  for (int ks = 0; ks < 8; ++ks) s += ws[PARTV_OFF + ks*16384 + i];
  ((short*)(ws + VBF_OFF))[i] = f2bf(s);
}

// bvec(32 x 12544) = v_bf(32x512) . W_box(12544x512)^T
__global__ __launch_bounds__(256) void k_bvec(const float* __restrict__ W_box,
                                              float* __restrict__ ws) {
  __shared__ __align__(16) short Bl[32*520];
  int tid = threadIdx.x;
  int j0 = blockIdx.x * 32;   // 392 blocks
  for (int j = 0; j < 64; ++j) {
    int id = tid + j*256;
    int row = id >> 9, kk = id & 511;
    Bl[row*520 + kk] = f2bf(W_box[(size_t)(j0+row)*512 + kk]);
  }
  __syncthreads();
  int w = tid >> 6, lane = tid & 63;
  int q = lane >> 4, m = lane & 15;
  int m0 = (w & 1) * 16, n0 = (w >> 1) * 16;
  const short* vbf = (const short*)(ws + VBF_OFF);
  f32x4 acc = {0.f,0.f,0.f,0.f};
  const short* ap = vbf + (m0 + m)*512 + q*8;
  const short* bp = Bl + (n0 + m)*520 + q*8;
  #pragma unroll
  for (int kk = 0; kk < 16; ++kk) {
    short8 a = *(const short8*)(ap + kk*32);
    short8 b = *(const short8*)(bp + kk*32);
    acc = __builtin_amdgcn_mfma_f32_16x16x32_bf16(a, b, acc, 0, 0, 0);
  }
  #pragma unroll
  for (int r = 0; r < 4; ++r) {
    int row = m0 + q*4 + r;
    int col = j0 + n0 + m;
    ws[BVEC_OFF + row*12544 + col] = acc[r];
  }
}

// gx(1568x64) = bvec . imgx^T ; gy(1568x48) = bvec . imgy^T
__global__ __launch_bounds__(256) void k_gxgy(float* __restrict__ ws) {
  __shared__ __align__(16) short Al[32*264];
  __shared__ __align__(16) short Bl[32*264];
  int tid = threadIdx.x;
  int bid = blockIdx.x;          // 196
  bool isgy = bid >= 98;
  int t = isgy ? bid - 98 : bid;
  int mb = t >> 1, nb = t & 1;
  for (int j = 0; j < 32; ++j) {
    int id = tid + j*256;
    int row = id >> 8, o = id & 255;
    Al[row*264 + o] = f2bf(ws[BVEC_OFF + (mb*32+row)*256 + o]);
  }
  for (int j = 0; j < 32; ++j) {
    int id = tid + j*256;
    int row = id >> 8, o = id & 255;
    int grow = nb*32 + row;
    float v;
    if (isgy) v = (grow < 48) ? ws[IMGY_OFF + grow*256 + o] : 0.f;
    else      v = ws[IMGX_OFF + grow*256 + o];
    Bl[row*264 + o] = f2bf(v);
  }
  __syncthreads();
  int w = tid >> 6, lane = tid & 63;
  int q = lane >> 4, m = lane & 15;
  int m0 = (w & 1)*16, n0 = (w >> 1)*16;
  f32x4 acc = {0.f,0.f,0.f,0.f};
  const short* ap = Al + (m0+m)*264 + q*8;
  const short* bp = Bl + (n0+m)*264 + q*8;
  #pragma unroll
  for (int kk = 0; kk < 8; ++kk) {
    short8 a = *(const short8*)(ap + kk*32);
    short8 b = *(const short8*)(bp + kk*32);
    acc = __builtin_amdgcn_mfma_f32_16x16x32_bf16(a, b, acc, 0, 0, 0);
  }
  #pragma unroll
  for (int r = 0; r < 4; ++r) {
    int row = mb*32 + m0 + q*4 + r;
    int col = nb*32 + n0 + m;
    if (isgy) { if (col < 48) ws[GY_OFF + row*48 + col] = acc[r]; }
    else      ws[GX_OFF + row*64 + col] = acc[r];
  }
}

// appT[b][p][k(pad52)] = x[b][:][p]^T . conv_w^T + conv_b
__global__ __launch_bounds__(256) void k_app(const float* __restrict__ x,
                                             const float* __restrict__ conv_w,
                                             const float* __restrict__ conv_b,
                                             float* __restrict__ ws) {
  __shared__ __align__(16) short Al[32*264];   // xT [p][c]
  __shared__ __align__(16) short Bl[64*264];   // conv_w, k padded to 64
  int tid = threadIdx.x;
  int b = blockIdx.x / 96, pt = blockIdx.x % 96;
  int p0 = pt * 32;
  const float* xb = x + (size_t)b * 786432;
  for (int j = 0; j < 32; ++j) {
    int id = tid + j*256;
    int c = id >> 5, pi = id & 31;
    Al[pi*264 + c] = f2bf(xb[c*3072 + p0 + pi]);
  }
  for (int j = 0; j < 64; ++j) {
    int id = tid + j*256;
    int k = id >> 8, c = id & 255;
    Bl[k*264 + c] = (k < 49) ? f2bf(conv_w[k*256 + c]) : (short)0;
  }
  __syncthreads();
  int w = tid >> 6, lane = tid & 63;
  int q = lane >> 4, m = lane & 15;
  int n0 = w * 16;
  f32x4 acc0 = {0.f,0.f,0.f,0.f}, acc1 = {0.f,0.f,0.f,0.f};
  const short* ap = Al + m*264 + q*8;
  const short* bp = Bl + (n0+m)*264 + q*8;
  #pragma unroll
  for (int kk = 0; kk < 8; ++kk) {
    short8 b8 = *(const short8*)(bp + kk*32);
    short8 a0 = *(const short8*)(ap + kk*32);
    short8 a1 = *(const short8*)(ap + 16*264 + kk*32);
    acc0 = __builtin_amdgcn_mfma_f32_16x16x32_bf16(a0, b8, acc0, 0,0,0);
    acc1 = __builtin_amdgcn_mfma_f32_16x16x32_bf16(a1, b8, acc1, 0,0,0);
  }
  int k = n0 + m;
  if (k < 49) {
    float bias = conv_b[k];
    float* apt = ws + APPT_OFF + (size_t)b*159744;
    #pragma unroll
    for (int r = 0; r < 4; ++r) {
      int p = p0 + q*4 + r;
      apt[(size_t)p*52 + k] = acc0[r] + bias;
      apt[(size_t)(p+16)*52 + k] = acc1[r] + bias;
    }
  }
}

__global__ __launch_bounds__(256) void k_final(const float* __restrict__ rois,
                                               const float* __restrict__ ws,
                                               float* __restrict__ out) {
  __shared__ float gxl[3136];
  __shared__ float gyl[2352];
  __shared__ int rank_sh;
  int tid = threadIdx.x;
  int bid = blockIdx.x;          // 1536 = 32n * 4b * 12 tiles
  int n = bid / 48;
  int rem = bid % 48;
  int b = rem / 12, tile = rem % 12;
  for (int j = 0; j < 13; ++j) {
    int id = tid + j*256;
    if (id < 3136) gxl[id] = ws[GX_OFF + n*3136 + id];
  }
  for (int j = 0; j < 10; ++j) {
    int id = tid + j*256;
    if (id < 2352) gyl[id] = ws[GY_OFF + n*2352 + id];
  }
  if (tid == 0) {
    float my = rois[n*5];
    int r = 0;
    for (int mm = 0; mm < 32; ++mm) {
      float vm = rois[mm*5];
      if (vm < my || (vm == my && mm < n)) ++r;
    }
    rank_sh = r;
  }
  __syncthreads();
  int pix = tile*256 + tid;
  int h = pix / 48, wv = pix - h*48;
  float lg[49];
  const float* ap = ws + APPT_OFF + (size_t)(b*3072 + pix)*52;
  #pragma unroll
  for (int qq = 0; qq < 12; ++qq) {
    float4 t = *(const float4*)(ap + qq*4);
    lg[qq*4+0] = t.x; lg[qq*4+1] = t.y; lg[qq*4+2] = t.z; lg[qq*4+3] = t.w;
  }
  lg[48] = ap[48];
  #pragma unroll
  for (int k = 0; k < 49; ++k)
    lg[k] += gxl[k*64 + h] + gyl[k*48 + wv];
  float mx = lg[0];
  #pragma unroll
  for (int k = 1; k < 49; ++k) mx = fmaxf(mx, lg[k]);
  float s = 0.f;
  #pragma unroll
  for (int k = 0; k < 49; ++k) { float e = __expf(lg[k]-mx); lg[k] = e; s += e; }
  float inv = 1.f / s;
  int r = rank_sh;
  float* op = out + (size_t)(r*4 + b)*150528 + pix;
  #pragma unroll
  for (int k = 0; k < 49; ++k)
    op[(size_t)k*3072] = lg[k]*inv;
}

extern "C" void kernel_launch(void* const* d_in, const int* in_sizes, int n_in,
                              void* d_out, int out_size, void* d_ws, size_t ws_size,
                              hipStream_t stream) {
  const float* x      = (const float*)d_in[0];
  const float* rois   = (const float*)d_in[1];
  const float* V_box  = (const float*)d_in[2];
  const float* W_box  = (const float*)d_in[3];
  const float* W_im   = (const float*)d_in[4];
  const float* conv_w = (const float*)d_in[5];
  const float* conv_b = (const float*)d_in[6];
  float* ws  = (float*)d_ws;
  float* out = (float*)d_out;

  hipLaunchKernelGGL(k_pre,   dim3(120),  dim3(256), 0, stream, rois, W_im, ws);
  hipLaunchKernelGGL(k_v,     dim3(128),  dim3(256), 0, stream, V_box, ws);
  hipLaunchKernelGGL(k_vred,  dim3(64),   dim3(256), 0, stream, ws);
  hipLaunchKernelGGL(k_bvec,  dim3(392),  dim3(256), 0, stream, W_box, ws);
  hipLaunchKernelGGL(k_gxgy,  dim3(196),  dim3(256), 0, stream, ws);
  hipLaunchKernelGGL(k_app,   dim3(384),  dim3(256), 0, stream, x, conv_w, conv_b, ws);
  hipLaunchKernelGGL(k_final, dim3(1536), dim3(256), 0, stream, rois, ws, out);
}

// Round 2
// 151.611 us; speedup vs baseline: 1.2791x; 1.2791x over previous
//
#include <hip/hip_runtime.h>

typedef __attribute__((ext_vector_type(8))) short short8;
typedef __attribute__((ext_vector_type(4))) short short4v;
typedef __attribute__((ext_vector_type(4))) float f32x4;

#define LN1000_OVER_512 0.0134917095f

// ws layout (f32 offsets)
#define EPS_OFF   0        // f32 [32][2048]
#define IMGB_OFF  65536    // bf16 [112][256] (rows 0..63 = x/h, 64..111 = y/w)
#define V_OFF     79872    // f32 [32][512]  (atomic accum, zeroed by K1)
#define GX_OFF    96256    // f32 [1568][64]
#define GY_OFF    196608   // f32 [1568][48]
#define BVB_OFF   271872   // bf16 [32][12544]  == [(n*49+k)][256]
#define APPT_OFF  472576   // f32 [4][3072][52] (k padded 49->52)

__device__ __forceinline__ short f2bf(float x) {
  unsigned u = __float_as_uint(x);
  return (short)((u + 0x7FFFu + ((u >> 16) & 1u)) >> 16);
}
__device__ __forceinline__ short4v f2bf4(float4 v) {
  short4v r; r.x = f2bf(v.x); r.y = f2bf(v.y); r.z = f2bf(v.z); r.w = f2bf(v.w);
  return r;
}

// K1: img rows (bf16) + eps + zero-V + app GEMM. All input-independent work.
__global__ __launch_bounds__(256) void k1(const float* __restrict__ rois,
                                          const float* __restrict__ W_im,
                                          const float* __restrict__ x,
                                          const float* __restrict__ conv_w,
                                          const float* __restrict__ conv_b,
                                          float* __restrict__ ws) {
  __shared__ __align__(16) short sh[96 * 264];   // app: Al(32x264)+Bl(64x264); img: el alias
  int bid = blockIdx.x, tid = threadIdx.x;
  short* imgb = (short*)(ws + IMGB_OFF);
  if (bid < 112) {
    // img row: imgb[row][o] = sum_d W_im[o][row<64 ? d : 512+d] * embed(pos)[d]
    float* el = (float*)sh;
    bool isx = bid < 64;
    int pos = isx ? bid : bid - 64;
    float z = (float)pos;
    for (int e = tid; e < 512; e += 256) {
      float inv = (e < 256) ? __expf(-LN1000_OVER_512 * (float)(2*e+1))
                            : __expf(-LN1000_OVER_512 * (float)(2*(e-256)));
      el[e] = (e < 256) ? __sinf(z * inv) : __cosf(z * inv);
    }
    __syncthreads();
    const float* wrow = W_im + tid * 1024 + (isx ? 0 : 512);
    float acc = 0.f;
    #pragma unroll 4
    for (int d = 0; d < 512; d += 4) {
      float4 wv = *(const float4*)(wrow + d);
      acc += wv.x*el[d] + wv.y*el[d+1] + wv.z*el[d+2] + wv.w*el[d+3];
    }
    imgb[bid * 256 + tid] = f2bf(acc);
  } else if (bid < 120) {
    // eps: 65536 elements over 8 blocks
    int id0 = (bid - 112) * 256 + tid;
    for (int r = 0; r < 32; ++r) {
      int id = id0 + r * 2048;
      int n = id >> 11, f = id & 2047;
      int c = f >> 9, e = f & 511;
      float z = rois[n*5 + 1 + c];
      float inv = (e < 256) ? __expf(-LN1000_OVER_512 * (float)(2*e+1))
                            : __expf(-LN1000_OVER_512 * (float)(2*(e-256)));
      ws[EPS_OFF + id] = (e < 256) ? __sinf(z*inv) : __cosf(z*inv);
    }
  } else if (bid == 120) {
    #pragma unroll
    for (int i = 0; i < 64; ++i) ws[V_OFF + tid + i*256] = 0.f;
  } else {
    // app: appT[b][p][k] = sum_c x[b][c][p] * conv_w[k][c] + conv_b[k]
    short* Al = sh;                  // [32 px][264] (c)
    short* Bl = sh + 32*264;         // [64 k][264] (c)
    int t = bid - 121;
    int b = t / 96, pt = t % 96;
    int p0 = pt * 32;
    const float* xb = x + (size_t)b * 786432;
    // A stage: 2048 float4 units; transpose writes are scalar b16 (unavoidable)
    #pragma unroll
    for (int j = 0; j < 8; ++j) {
      int fid = tid + j*256;
      int c = fid >> 3, pj = fid & 7;
      float4 v = *(const float4*)(xb + c*3072 + p0 + pj*4);
      Al[(pj*4+0)*264 + c] = f2bf(v.x);
      Al[(pj*4+1)*264 + c] = f2bf(v.y);
      Al[(pj*4+2)*264 + c] = f2bf(v.z);
      Al[(pj*4+3)*264 + c] = f2bf(v.w);
    }
    #pragma unroll
    for (int j = 0; j < 16; ++j) {
      int fid = tid + j*256;
      int k = fid >> 6, c4 = fid & 63;
      short4v s4 = {0,0,0,0};
      if (k < 49) s4 = f2bf4(*(const float4*)(conv_w + k*256 + c4*4));
      *(short4v*)(Bl + k*264 + c4*4) = s4;
    }
    __syncthreads();
    int w = tid >> 6, lane = tid & 63;
    int q = lane >> 4, m = lane & 15;
    int n0 = w * 16;
    f32x4 acc0 = {0.f,0.f,0.f,0.f}, acc1 = {0.f,0.f,0.f,0.f};
    const short* ap = Al + m*264 + q*8;
    const short* bp = Bl + (n0+m)*264 + q*8;
    #pragma unroll
    for (int kk = 0; kk < 8; ++kk) {
      short8 b8 = *(const short8*)(bp + kk*32);
      short8 a0 = *(const short8*)(ap + kk*32);
      short8 a1 = *(const short8*)(ap + 16*264 + kk*32);
      acc0 = __builtin_amdgcn_mfma_f32_16x16x32_bf16(a0, b8, acc0, 0,0,0);
      acc1 = __builtin_amdgcn_mfma_f32_16x16x32_bf16(a1, b8, acc1, 0,0,0);
    }
    int k = n0 + m;
    if (k < 49) {
      float bias = conv_b[k];
      float* apt = ws + APPT_OFF + (size_t)b * 159744;
      #pragma unroll
      for (int r = 0; r < 4; ++r) {
        int p = p0 + q*4 + r;
        apt[(size_t)p*52 + k] = acc0[r] + bias;
        apt[(size_t)(p+16)*52 + k] = acc1[r] + bias;
      }
    }
  }
}

// K2: v[32][512] += eps(32x2048) . V_box(512x2048)^T, K-split x8, f32 atomics
__global__ __launch_bounds__(256) void k2(const float* __restrict__ V_box,
                                          float* __restrict__ ws) {
  __shared__ __align__(16) short Al[32*264];
  __shared__ __align__(16) short Bl[32*264];
  int tid = threadIdx.x;
  int ntb = blockIdx.x & 15, ks = blockIdx.x >> 4;
  int k0 = ks * 256, d0 = ntb * 32;
  #pragma unroll
  for (int j = 0; j < 8; ++j) {
    int fid = tid + j*256;
    int n = fid >> 6, k4 = fid & 63;
    float4 v = *(const float4*)(ws + EPS_OFF + n*2048 + k0 + k4*4);
    *(short4v*)(Al + n*264 + k4*4) = f2bf4(v);
  }
  #pragma unroll
  for (int j = 0; j < 8; ++j) {
    int fid = tid + j*256;
    int dd = fid >> 6, k4 = fid & 63;
    float4 v = *(const float4*)(V_box + (size_t)(d0+dd)*2048 + k0 + k4*4);
    *(short4v*)(Bl + dd*264 + k4*4) = f2bf4(v);
  }
  __syncthreads();
  int w = tid >> 6, lane = tid & 63;
  int q = lane >> 4, m = lane & 15;
  int m0 = (w & 1)*16, n0 = (w >> 1)*16;
  f32x4 acc = {0.f,0.f,0.f,0.f};
  const short* ap = Al + (m0+m)*264 + q*8;
  const short* bp = Bl + (n0+m)*264 + q*8;
  #pragma unroll
  for (int kk = 0; kk < 8; ++kk) {
    short8 a = *(const short8*)(ap + kk*32);
    short8 b = *(const short8*)(bp + kk*32);
    acc = __builtin_amdgcn_mfma_f32_16x16x32_bf16(a, b, acc, 0, 0, 0);
  }
  #pragma unroll
  for (int r = 0; r < 4; ++r) {
    int row = m0 + q*4 + r;
    int col = d0 + n0 + m;
    unsafeAtomicAdd(&ws[V_OFF + row*512 + col], acc[r]);
  }
}

// K3: bvec_bf16[n][12544] = v(32x512) . W_box(12544x512)^T
__global__ __launch_bounds__(256) void k3(const float* __restrict__ W_box,
                                          float* __restrict__ ws) {
  __shared__ __align__(16) short Av[32*520];
  __shared__ __align__(16) short Bl[32*520];
  int tid = threadIdx.x;
  int j0 = blockIdx.x * 32;   // 392 blocks
  #pragma unroll
  for (int j = 0; j < 16; ++j) {
    int fid = tid + j*256;
    int n = fid >> 7, d4 = fid & 127;
    float4 v = *(const float4*)(ws + V_OFF + n*512 + d4*4);
    *(short4v*)(Av + n*520 + d4*4) = f2bf4(v);
  }
  #pragma unroll
  for (int j = 0; j < 16; ++j) {
    int fid = tid + j*256;
    int rr = fid >> 7, d4 = fid & 127;
    float4 v = *(const float4*)(W_box + (size_t)(j0+rr)*512 + d4*4);
    *(short4v*)(Bl + rr*520 + d4*4) = f2bf4(v);
  }
  __syncthreads();
  int w = tid >> 6, lane = tid & 63;
  int q = lane >> 4, m = lane & 15;
  int m0 = (w & 1)*16, n0 = (w >> 1)*16;
  f32x4 acc = {0.f,0.f,0.f,0.f};
  const short* ap = Av + (m0+m)*520 + q*8;
  const short* bp = Bl + (n0+m)*520 + q*8;
  #pragma unroll
  for (int kk = 0; kk < 16; ++kk) {
    short8 a = *(const short8*)(ap + kk*32);
    short8 b = *(const short8*)(bp + kk*32);
    acc = __builtin_amdgcn_mfma_f32_16x16x32_bf16(a, b, acc, 0, 0, 0);
  }
  short* bvb = (short*)(ws + BVB_OFF);
  #pragma unroll
  for (int r = 0; r < 4; ++r) {
    int row = m0 + q*4 + r;
    int col = j0 + n0 + m;
    bvb[(size_t)row*12544 + col] = f2bf(acc[r]);
  }
}

// K4: gx[1568][64] = bvec . imgx^T ; gy[1568][48] = bvec . imgy^T
//     A staged bf16 from global; B fragments read directly from L2-hot imgb.
__global__ __launch_bounds__(256) void k4(float* __restrict__ ws) {
  __shared__ __align__(16) short Al[32*264];
  int tid = threadIdx.x;
  int half = blockIdx.x & 1, rb = blockIdx.x >> 1;   // 98 blocks
  int r0 = rb * 32;
  const short* bvb = (const short*)(ws + BVB_OFF);
  #pragma unroll
  for (int j = 0; j < 4; ++j) {
    int fid = tid + j*256;
    int rr = fid >> 5, o8 = fid & 31;
    *(short8*)(Al + rr*264 + o8*8) = *(const short8*)(bvb + (size_t)(r0+rr)*256 + o8*8);
  }
  __syncthreads();
  int w = tid >> 6, lane = tid & 63;
  int q = lane >> 4, m = lane & 15;
  int nct = half ? 3 : 4;
  if (w < nct) {
    const short* imgb = (const short*)(ws + IMGB_OFF) + (half ? 64*256 : 0);
    int ct = w;
    f32x4 acc0 = {0.f,0.f,0.f,0.f}, acc1 = {0.f,0.f,0.f,0.f};
    const short* ap0 = Al + m*264 + q*8;
    const short* ap1 = Al + (16+m)*264 + q*8;
    const short* bp  = imgb + (ct*16+m)*256 + q*8;
    #pragma unroll
    for (int kk = 0; kk < 8; ++kk) {
      short8 b8 = *(const short8*)(bp + kk*32);
      short8 a0 = *(const short8*)(ap0 + kk*32);
      short8 a1 = *(const short8*)(ap1 + kk*32);
      acc0 = __builtin_amdgcn_mfma_f32_16x16x32_bf16(a0, b8, acc0, 0,0,0);
      acc1 = __builtin_amdgcn_mfma_f32_16x16x32_bf16(a1, b8, acc1, 0,0,0);
    }
    float* outp = ws + (half ? GY_OFF : GX_OFF);
    int stride = half ? 48 : 64;
    int col = ct*16 + m;
    #pragma unroll
    for (int r = 0; r < 4; ++r) {
      outp[(r0 + q*4 + r)*stride + col]      = acc0[r];
      outp[(r0 + 16 + q*4 + r)*stride + col] = acc1[r];
    }
  }
}

// K5: logits = appT + gx + gy -> softmax over k -> ordered write
__global__ __launch_bounds__(256) void k5(const float* __restrict__ rois,
                                          const float* __restrict__ ws,
                                          float* __restrict__ out) {
  __shared__ float gxl[3136];
  __shared__ float gyl[2352];
  __shared__ int rank_sh;
  int tid = threadIdx.x, bid = blockIdx.x;   // 384 = 32 n x 12 tiles
  int n = bid / 12, tile = bid % 12;
  #pragma unroll
  for (int j = 0; j < 4; ++j) {
    int id = tid + j*256;
    if (id < 784) *(float4*)(gxl + id*4) = *(const float4*)(ws + GX_OFF + n*3136 + id*4);
  }
  #pragma unroll
  for (int j = 0; j < 3; ++j) {
    int id = tid + j*256;
    if (id < 588) *(float4*)(gyl + id*4) = *(const float4*)(ws + GY_OFF + n*2352 + id*4);
  }
  if (tid == 0) {
    float my = rois[n*5];
    int r = 0;
    for (int mm = 0; mm < 32; ++mm) {
      float vm = rois[mm*5];
      if (vm < my || (vm == my && mm < n)) ++r;
    }
    rank_sh = r;
  }
  __syncthreads();
  int pix = tile*256 + tid;
  int h = pix / 48, wv = pix - h*48;
  int r = rank_sh;
  for (int b = 0; b < 4; ++b) {
    const float* ap = ws + APPT_OFF + (size_t)(b*3072 + pix)*52;
    float lg[49];
    #pragma unroll
    for (int qq = 0; qq < 12; ++qq) {
      float4 t = *(const float4*)(ap + qq*4);
      lg[qq*4+0] = t.x; lg[qq*4+1] = t.y; lg[qq*4+2] = t.z; lg[qq*4+3] = t.w;
    }
    lg[48] = ap[48];
    #pragma unroll
    for (int k = 0; k < 49; ++k)
      lg[k] += gxl[k*64 + h] + gyl[k*48 + wv];
    float mx = lg[0];
    #pragma unroll
    for (int k = 1; k < 49; ++k) mx = fmaxf(mx, lg[k]);
    float s = 0.f;
    #pragma unroll
    for (int k = 0; k < 49; ++k) { float e = __expf(lg[k]-mx); lg[k] = e; s += e; }
    float inv = 1.f / s;
    float* op = out + (size_t)(r*4 + b)*150528 + pix;
    #pragma unroll
    for (int k = 0; k < 49; ++k)
      op[(size_t)k*3072] = lg[k]*inv;
  }
}

extern "C" void kernel_launch(void* const* d_in, const int* in_sizes, int n_in,
                              void* d_out, int out_size, void* d_ws, size_t ws_size,
                              hipStream_t stream) {
  const float* x      = (const float*)d_in[0];
  const float* rois   = (const float*)d_in[1];
  const float* V_box  = (const float*)d_in[2];
  const float* W_box  = (const float*)d_in[3];
  const float* W_im   = (const float*)d_in[4];
  const float* conv_w = (const float*)d_in[5];
  const float* conv_b = (const float*)d_in[6];
  float* ws  = (float*)d_ws;
  float* out = (float*)d_out;

  hipLaunchKernelGGL(k1, dim3(505), dim3(256), 0, stream, rois, W_im, x, conv_w, conv_b, ws);
  hipLaunchKernelGGL(k2, dim3(128), dim3(256), 0, stream, V_box, ws);
  hipLaunchKernelGGL(k3, dim3(392), dim3(256), 0, stream, W_box, ws);
  hipLaunchKernelGGL(k4, dim3(98),  dim3(256), 0, stream, ws);
  hipLaunchKernelGGL(k5, dim3(384), dim3(256), 0, stream, rois, ws, out);
}